// Round 2
// baseline (1713.256 us; speedup 1.0000x reference)
//
#include <hip/hip_runtime.h>
#include <hip/hip_bf16.h>

typedef unsigned short u16;
typedef __attribute__((ext_vector_type(8))) short bf16x8;
typedef __attribute__((ext_vector_type(4))) float f32x4;

#define MFMA16(a, b, c) __builtin_amdgcn_mfma_f32_16x16x32_bf16((a), (b), (c), 0, 0, 0)

__device__ __forceinline__ float bf2f(u16 u) {
    union { unsigned int i; float f; } v;
    v.i = ((unsigned int)u) << 16;
    return v.f;
}
__device__ __forceinline__ u16 f2bf(float f) {
    unsigned int x = __float_as_uint(f);
    x += 0x7FFFu + ((x >> 16) & 1u);   // RNE
    return (u16)(x >> 16);
}

// ---------------------------------------------------------------------------
// rope table: tab[s][p] = (cos, sin)(pos * 10000^(-p/16)), pos = 8976 + s
// double math to match numpy's fp64 table then fp32 cast.
// ---------------------------------------------------------------------------
__global__ void rope_table_kernel(float2* __restrict__ tab) {
    int i = blockIdx.x * 256 + threadIdx.x;
    if (i >= 1024 * 16) return;
    int s = i >> 4, p = i & 15;
    double ang = (double)(8976 + s) * pow(10000.0, -(double)p / 16.0);
    tab[i] = make_float2((float)cos(ang), (float)sin(ang));
}

// ---------------------------------------------------------------------------
// In-place partial rotary on first 32 channels of q and k (bf16 ws buffers).
// One thread owns one (b,s,h) -> race-free in-place.
// ---------------------------------------------------------------------------
__global__ void rope_apply_kernel(u16* __restrict__ q, u16* __restrict__ k,
                                  const float2* __restrict__ tab) {
    int i = blockIdx.x * 256 + threadIdx.x;   // (b*1024 + s)*32 + h
    if (i >= 4 * 1024 * 32) return;
    int s = (i >> 5) & 1023;
    const float2* tp = tab + s * 16;
    u16* ptrs[2] = { q + (size_t)i * 128, k + (size_t)i * 128 };
#pragma unroll
    for (int t = 0; t < 2; t++) {
        u16* p = ptrs[t];
        u16 buf[32], outb[32];
        *(uint4*)(buf)      = *(const uint4*)(p);
        *(uint4*)(buf + 8)  = *(const uint4*)(p + 8);
        *(uint4*)(buf + 16) = *(const uint4*)(p + 16);
        *(uint4*)(buf + 24) = *(const uint4*)(p + 24);
#pragma unroll
        for (int j = 0; j < 16; j++) {
            float a = bf2f(buf[j]), b = bf2f(buf[j + 16]);
            float c = tp[j].x, sn = tp[j].y;
            outb[2 * j]     = f2bf(a * c - b * sn);
            outb[2 * j + 1] = f2bf(a * sn + b * c);
        }
        *(uint4*)(p)      = *(uint4*)(outb);
        *(uint4*)(p + 8)  = *(uint4*)(outb + 8);
        *(uint4*)(p + 16) = *(uint4*)(outb + 16);
        *(uint4*)(p + 24) = *(uint4*)(outb + 24);
    }
}

// ---------------------------------------------------------------------------
// C[M,N] = X[M,K] * W[K,N] + bias[N].
// A_F32: X is fp32 (converted to bf16 in staging) else bf16.
// OUT_F32: C written fp32 else bf16. W/bias always fp32. fp32 accum via MFMA.
// 128x128 tile, BK=32, 256 threads (4 waves, 2x2 of 64x64 each = 4x4 MFMA).
// As: [m][k] stride 32 shorts; Bs: [n][k] stride 40 shorts (16B-aligned rows).
// ---------------------------------------------------------------------------
template<int A_F32, int OUT_F32>
__global__ __launch_bounds__(256) void gemm_bias_kernel(
    const void* __restrict__ Xv, const float* __restrict__ W,
    const float* __restrict__ bias, void* __restrict__ Cv,
    int M, int N, int K) {
    constexpr int BK = 32;
    constexpr int BS = 40;
    __shared__ u16 As[128 * BK];
    __shared__ u16 Bs[128 * BS];

    const int tid  = threadIdx.x;
    const int lane = tid & 63;
    const int wave = tid >> 6;
    const int quad = lane >> 4;
    const int lm   = lane & 15;
    const int m0 = blockIdx.y * 128;
    const int n0 = blockIdx.x * 128;
    const int wm = (wave >> 1) * 64;
    const int wn = (wave & 1) * 64;

    const f32x4 fz = {0.f, 0.f, 0.f, 0.f};
    f32x4 acc[4][4];
#pragma unroll
    for (int i = 0; i < 4; i++)
#pragma unroll
        for (int j = 0; j < 4; j++) acc[i][j] = fz;

    for (int k0 = 0; k0 < K; k0 += BK) {
        // stage A: 128 rows x 32 k
#pragma unroll
        for (int i = 0; i < 2; i++) {
            int c = tid + i * 256;
            int row = c >> 2, part = c & 3;
            if (A_F32) {
                const float* src = (const float*)Xv + (size_t)(m0 + row) * K + k0 + part * 8;
                float4 f0 = *(const float4*)(src);
                float4 f1 = *(const float4*)(src + 4);
                u16 t[8] = { f2bf(f0.x), f2bf(f0.y), f2bf(f0.z), f2bf(f0.w),
                             f2bf(f1.x), f2bf(f1.y), f2bf(f1.z), f2bf(f1.w) };
                *(uint4*)(As + row * BK + part * 8) = *(uint4*)t;
            } else {
                const uint4* src = (const uint4*)((const u16*)Xv + (size_t)(m0 + row) * K + k0 + part * 8);
                *(uint4*)(As + row * BK + part * 8) = *src;
            }
        }
        // stage B transposed: thread gathers 8 k-strided fp32 of one n column
#pragma unroll
        for (int i = 0; i < 2; i++) {
            int w = tid + i * 256;
            int n = w & 127, kc = w >> 7;
            const float* src = W + (size_t)(k0 + kc * 8) * N + (n0 + n);
            union { u16 u[8]; uint4 v; } t;
#pragma unroll
            for (int j = 0; j < 8; j++) t.u[j] = f2bf(src[(size_t)j * N]);
            *(uint4*)(Bs + n * BS + kc * 8) = t.v;
        }
        __syncthreads();

        bf16x8 a[4], b[4];
#pragma unroll
        for (int i = 0; i < 4; i++)
            a[i] = *(const bf16x8*)(As + (wm + i * 16 + lm) * BK + quad * 8);
#pragma unroll
        for (int i = 0; i < 4; i++)
            b[i] = *(const bf16x8*)(Bs + (wn + i * 16 + lm) * BS + quad * 8);
#pragma unroll
        for (int i = 0; i < 4; i++)
#pragma unroll
            for (int j = 0; j < 4; j++)
                acc[i][j] = MFMA16(a[i], b[j], acc[i][j]);
        __syncthreads();
    }

    // epilogue: C/D layout col=lane&15, row=quad*4+reg
#pragma unroll
    for (int j = 0; j < 4; j++) {
        int col = n0 + wn + j * 16 + lm;
        float bv = bias[col];
#pragma unroll
        for (int i = 0; i < 4; i++) {
            int rowb = m0 + wm + i * 16 + quad * 4;
#pragma unroll
            for (int r = 0; r < 4; r++) {
                float v = acc[i][j][r] + bv;
                if (OUT_F32) ((float*)Cv)[(size_t)(rowb + r) * N + col] = v;
                else         ((u16*)Cv)[(size_t)(rowb + r) * N + col] = f2bf(v);
            }
        }
    }
}

// ---------------------------------------------------------------------------
// Flash attention, exact online softmax. q/k/v bf16 (ws), Bias fp32, O bf16.
// Block = (q_tile of 64 rows, h, b); 4 waves x 16 q-rows each.
// ---------------------------------------------------------------------------
__global__ __launch_bounds__(256) void attn_kernel(
    const u16* __restrict__ Q, const u16* __restrict__ Kv,
    const u16* __restrict__ V, const float* __restrict__ Bias,
    u16* __restrict__ O) {
    constexpr int S = 1024, H = 32, HD = 128;
    constexpr int KST = 136;   // 272B rows: 16B aligned, banks spread
    constexpr int VST = 40;    // 80B rows
    __shared__ u16 Ks[32 * KST];
    __shared__ u16 Vst[128 * VST];
    __shared__ u16 Ps[4 * 16 * VST];

    const int tid  = threadIdx.x;
    const int lane = tid & 63;
    const int wave = tid >> 6;
    const int quad = lane >> 4;
    const int lm   = lane & 15;
    const int qt = blockIdx.x;
    const int h  = blockIdx.y;
    const int b  = blockIdx.z;
    const int qrow = qt * 64 + wave * 16;

    // Q fragments (A-operand), held in registers across the whole loop
    const u16* qb = Q + (((size_t)b * S + qrow + lm) * H + h) * HD;
    bf16x8 qf[4];
#pragma unroll
    for (int f = 0; f < 4; f++)
        qf[f] = *(const bf16x8*)(qb + f * 32 + quad * 8);

    float m_run[4], l_run[4], alpha[4];
#pragma unroll
    for (int r = 0; r < 4; r++) { m_run[r] = -3.0e38f; l_run[r] = 0.f; }
    const f32x4 fz = {0.f, 0.f, 0.f, 0.f};
    f32x4 oacc[8];
#pragma unroll
    for (int t = 0; t < 8; t++) oacc[t] = fz;

    const float scale = 0.08838834764831845f;  // 1/sqrt(128)

    for (int kt = 0; kt < S / 32; kt++) {
        const int key0 = kt * 32;
        // stage K natural [key][hd]
#pragma unroll
        for (int i = 0; i < 2; i++) {
            int c = tid + i * 256;
            int row = c >> 4, part = c & 15;
            const uint4* src = (const uint4*)(Kv + (((size_t)b * S + key0 + row) * H + h) * HD + part * 8);
            *(uint4*)(Ks + row * KST + part * 8) = *src;
        }
        // stage V transposed [hd][key]
#pragma unroll
        for (int i = 0; i < 2; i++) {
            int w = tid + i * 256;
            int hd = w & 127, kc = w >> 7;
            const u16* src = V + (((size_t)b * S + key0 + kc * 8) * H + h) * HD + hd;
            union { u16 u[8]; uint4 v; } t;
#pragma unroll
            for (int j = 0; j < 8; j++) t.u[j] = src[(size_t)j * H * HD];
            *(uint4*)(Vst + hd * VST + kc * 8) = t.v;
        }
        __syncthreads();

        // QK^T: two 16x16 score tiles (kt2 = 0,1), accumulate over HD
        f32x4 sc[2];
#pragma unroll
        for (int kt2 = 0; kt2 < 2; kt2++) {
            f32x4 c = fz;
#pragma unroll
            for (int f = 0; f < 4; f++) {
                bf16x8 kf = *(const bf16x8*)(Ks + (kt2 * 16 + lm) * KST + f * 32 + quad * 8);
                c = MFMA16(qf[f], kf, c);
            }
            sc[kt2] = c;
        }

        // online softmax per row (row = quad*4+r, its 16 cols live in the quad's lanes)
#pragma unroll
        for (int r = 0; r < 4; r++) {
            int qr = qrow + quad * 4 + r;
            float s0 = sc[0][r] * scale + Bias[(size_t)qr * S + key0 + lm];
            float s1 = sc[1][r] * scale + Bias[(size_t)qr * S + key0 + 16 + lm];
            float mx = fmaxf(s0, s1);
#pragma unroll
            for (int d = 1; d < 16; d <<= 1) mx = fmaxf(mx, __shfl_xor(mx, d));
            float mnew = fmaxf(m_run[r], mx);
            alpha[r] = __expf(m_run[r] - mnew);
            float p0 = __expf(s0 - mnew);
            float p1 = __expf(s1 - mnew);
            float ps = p0 + p1;
#pragma unroll
            for (int d = 1; d < 16; d <<= 1) ps += __shfl_xor(ps, d);
            l_run[r] = l_run[r] * alpha[r] + ps;
            m_run[r] = mnew;
            // P in C-layout -> per-wave LDS buffer for A-operand transpose
            Ps[wave * (16 * VST) + (quad * 4 + r) * VST + lm]      = f2bf(p0);
            Ps[wave * (16 * VST) + (quad * 4 + r) * VST + 16 + lm] = f2bf(p1);
        }
#pragma unroll
        for (int t = 0; t < 8; t++)
#pragma unroll
            for (int r = 0; r < 4; r++) oacc[t][r] *= alpha[r];
        __syncthreads();

        // PV: P as A-operand from LDS, V^T tiles as B-operand
        bf16x8 pf = *(const bf16x8*)(Ps + wave * (16 * VST) + lm * VST + quad * 8);
#pragma unroll
        for (int t = 0; t < 8; t++) {
            bf16x8 vf = *(const bf16x8*)(Vst + (t * 16 + lm) * VST + quad * 8);
            oacc[t] = MFMA16(pf, vf, oacc[t]);
        }
        __syncthreads();  // protect Ks/Vst before next iteration's staging
    }

    // epilogue: O /= l
    u16* ob = O + (((size_t)b * S + qrow) * H + h) * HD;
#pragma unroll
    for (int r = 0; r < 4; r++) {
        float inv = 1.0f / l_run[r];
#pragma unroll
        for (int t = 0; t < 8; t++) {
            int hd = t * 16 + lm;
            ob[(size_t)(quad * 4 + r) * H * HD + hd] = f2bf(oacc[t][r] * inv);
        }
    }
}

// ---------------------------------------------------------------------------
extern "C" void kernel_launch(void* const* d_in, const int* in_sizes, int n_in,
                              void* d_out, int out_size, void* d_ws, size_t ws_size,
                              hipStream_t stream) {
    const float* x   = (const float*)d_in[0];
    const float* ab  = (const float*)d_in[1];
    const float* wq  = (const float*)d_in[2];
    const float* wqb = (const float*)d_in[3];
    const float* wk  = (const float*)d_in[4];
    const float* wkb = (const float*)d_in[5];
    const float* wv  = (const float*)d_in[6];
    const float* wvb = (const float*)d_in[7];
    const float* wo  = (const float*)d_in[8];
    const float* wob = (const float*)d_in[9];
    float* out = (float*)d_out;

    const size_t MAT = (size_t)4096 * 4096;
    u16* qb = (u16*)d_ws;
    u16* kb = qb + MAT;
    u16* vb = kb + MAT;
    u16* ob = vb + MAT;
    float2* tab = (float2*)(ob + MAT);

    rope_table_kernel<<<64, 256, 0, stream>>>(tab);
    dim3 g(32, 32);
    gemm_bias_kernel<1, 0><<<g, 256, 0, stream>>>(x, wq, wqb, qb, 4096, 4096, 4096);
    gemm_bias_kernel<1, 0><<<g, 256, 0, stream>>>(x, wk, wkb, kb, 4096, 4096, 4096);
    gemm_bias_kernel<1, 0><<<g, 256, 0, stream>>>(x, wv, wvb, vb, 4096, 4096, 4096);
    rope_apply_kernel<<<512, 256, 0, stream>>>(qb, kb, tab);
    attn_kernel<<<dim3(16, 32, 4), 256, 0, stream>>>(qb, kb, vb, ab, ob);
    gemm_bias_kernel<0, 1><<<g, 256, 0, stream>>>(ob, wo, wob, out, 4096, 4096, 4096);
}